// Round 4
// baseline (5035.554 us; speedup 1.0000x reference)
//
#include <hip/hip_runtime.h>
#include <hip/hip_bf16.h>

#define T_LEN 2048
#define DMODEL 1024
#define DINNER 2048
#define DSTATE 16
#define LN_EPS 1e-5f

// ---------- LayerNorm: one thread per row (obviously correct) ----------
__global__ void ln_simple(const float* __restrict__ x, const float* __restrict__ g,
                          const float* __restrict__ b, float* __restrict__ xn) {
    int row = blockIdx.x * blockDim.x + threadIdx.x;
    if (row >= T_LEN) return;
    const float* xr = x + (size_t)row * DMODEL;
    float s = 0.f;
    for (int i = 0; i < DMODEL; i++) s += xr[i];
    float mu = s * (1.f / DMODEL);
    float q = 0.f;
    for (int i = 0; i < DMODEL; i++) { float dd = xr[i] - mu; q += dd * dd; }
    float rstd = rsqrtf(q * (1.f / DMODEL) + LN_EPS);
    float* o = xn + (size_t)row * DMODEL;
    for (int i = 0; i < DMODEL; i++) o[i] = (xr[i] - mu) * rstd * g[i] + b[i];
}

// ---------- Naive GEMM: xz[2048,4096] = xn[2048,1024] @ W_in[1024,4096] ----------
__global__ void gemm_in(const float* __restrict__ A, const float* __restrict__ B,
                        float* __restrict__ C) {
    int col = blockIdx.x * blockDim.x + threadIdx.x;
    int row = blockIdx.y;
    if (col >= 2 * DINNER || row >= T_LEN) return;
    float acc = 0.f;
    for (int k = 0; k < DMODEL; k++)
        acc += A[(size_t)row * DMODEL + k] * B[(size_t)k * (2 * DINNER) + col];
    C[(size_t)row * (2 * DINNER) + col] = acc;
}

// ---------- Causal depthwise conv(4) + SiLU ----------
__global__ void conv_silu(const float* __restrict__ xz, const float* __restrict__ cw,
                          const float* __restrict__ cb, float* __restrict__ xc) {
    int idx = blockIdx.x * blockDim.x + threadIdx.x;
    if (idx >= T_LEN * DINNER) return;
    int t = idx / DINNER, d = idx % DINNER;
    float acc = cb[d];
    for (int k = 0; k < 4; k++) {
        int tt = t - 3 + k;
        if (tt >= 0) acc += xz[(size_t)tt * (2 * DINNER) + d] * cw[d * 4 + k];
    }
    xc[idx] = acc / (1.f + expf(-acc));
}

// ---------- ssm[t, 0..32] = xc[t,:] @ W_x[2048,33] ----------
__global__ void proj_ssm(const float* __restrict__ xc, const float* __restrict__ Wx,
                         float* __restrict__ ssm) {
    int t = blockIdx.x;
    int c = threadIdx.x;
    if (c >= 33 || t >= T_LEN) return;
    float acc = 0.f;
    for (int k = 0; k < DINNER; k++)
        acc += xc[(size_t)t * DINNER + k] * Wx[(size_t)k * 33 + c];
    ssm[t * 33 + c] = acc;
}

// ---------- Selective scan, one thread per channel d ----------
__global__ void scan_k(const float* __restrict__ ssm, const float* __restrict__ xc,
                       const float* __restrict__ xz,
                       const float* __restrict__ Wdt, const float* __restrict__ bdt,
                       const float* __restrict__ Alog, const float* __restrict__ Dp,
                       float* __restrict__ yf) {
    int d = blockIdx.x * blockDim.x + threadIdx.x;
    if (d >= DINNER) return;
    float A[DSTATE], h[DSTATE];
    for (int n = 0; n < DSTATE; n++) {
        A[n] = -expf(Alog[d * DSTATE + n]);
        h[n] = 0.f;
    }
    float wdt = Wdt[d], bd = bdt[d], Dd = Dp[d];
    for (int t = 0; t < T_LEN; t++) {
        const float* srow = ssm + t * 33;
        float pre = srow[0] * wdt + bd;
        float dt = (pre > 20.f) ? pre : log1pf(expf(pre));
        float xcv = xc[(size_t)t * DINNER + d];
        float dtxc = dt * xcv;
        float y = 0.f;
        for (int n = 0; n < DSTATE; n++) {
            h[n] = expf(dt * A[n]) * h[n] + dtxc * srow[1 + n];
            y += h[n] * srow[17 + n];
        }
        float z = xz[(size_t)t * (2 * DINNER) + DINNER + d];
        float sz = z / (1.f + expf(-z));
        yf[(size_t)t * DINNER + d] = (y + xcv * Dd) * sz;
    }
}

// ---------- out[2048,1024] = yf[2048,2048] @ W_out[2048,1024] + x, fp32 store ----------
__global__ void gemm_out(const float* __restrict__ A, const float* __restrict__ B,
                         const float* __restrict__ resid, float* __restrict__ C) {
    int col = blockIdx.x * blockDim.x + threadIdx.x;
    int row = blockIdx.y;
    if (col >= DMODEL || row >= T_LEN) return;
    float acc = resid[(size_t)row * DMODEL + col];
    for (int k = 0; k < DINNER; k++)
        acc += A[(size_t)row * DINNER + k] * B[(size_t)k * DMODEL + col];
    C[(size_t)row * DMODEL + col] = acc;   // fp32 output (reference output dtype)
}

extern "C" void kernel_launch(void* const* d_in, const int* in_sizes, int n_in,
                              void* d_out, int out_size, void* d_ws, size_t ws_size,
                              hipStream_t stream) {
    const float* x     = (const float*)d_in[0];
    const float* W_in  = (const float*)d_in[1];
    const float* convw = (const float*)d_in[2];
    const float* convb = (const float*)d_in[3];
    const float* W_x   = (const float*)d_in[4];
    const float* W_dt  = (const float*)d_in[5];
    const float* b_dt  = (const float*)d_in[6];
    const float* A_log = (const float*)d_in[7];
    const float* Dp    = (const float*)d_in[8];
    const float* W_out = (const float*)d_in[9];
    const float* ln_g  = (const float*)d_in[10];
    const float* ln_b  = (const float*)d_in[11];
    float* out = (float*)d_out;

    // fp32 workspace, 72.3 MB total (round-1 proved >= 75.8 MB writable)
    char* wsb = (char*)d_ws;
    float* xn  = (float*)(wsb);                    //  8 MB: 2048x1024
    float* xz  = (float*)(wsb + (8ull  << 20));    // 32 MB: 2048x4096
    float* xc  = (float*)(wsb + (40ull << 20));    // 16 MB: 2048x2048
    float* yf  = (float*)(wsb + (56ull << 20));    // 16 MB: 2048x2048
    float* ssm = (float*)(wsb + (72ull << 20));    // 270 KB: 2048x33

    ln_simple<<<T_LEN / 256, 256, 0, stream>>>(x, ln_g, ln_b, xn);

    gemm_in<<<dim3((2 * DINNER) / 256, T_LEN), 256, 0, stream>>>(xn, W_in, xz);

    conv_silu<<<(T_LEN * DINNER) / 256, 256, 0, stream>>>(xz, convw, convb, xc);

    proj_ssm<<<T_LEN, 64, 0, stream>>>(xc, W_x, ssm);

    scan_k<<<DINNER / 256, 256, 0, stream>>>(ssm, xc, xz, W_dt, b_dt, A_log, Dp, yf);

    gemm_out<<<dim3(DMODEL / 256, T_LEN), 256, 0, stream>>>(yf, W_out, x, out);
}

// Round 5
// 970.855 us; speedup vs baseline: 5.1867x; 5.1867x over previous
//
#include <hip/hip_runtime.h>
#include <hip/hip_bf16.h>

#define T_LEN 2048
#define DMODEL 1024
#define DINNER 2048
#define DSTATE 16
#define LN_EPS 1e-5f
#define NCHUNK 32
#define CLEN 64   // NCHUNK * CLEN == T_LEN

// ---------- LayerNorm: one block (256 thr) per row ----------
__global__ void ln_kernel(const float* __restrict__ x, const float* __restrict__ g,
                          const float* __restrict__ b, float* __restrict__ xn) {
    int row = blockIdx.x;
    int tid = threadIdx.x;
    const float* xr = x + (size_t)row * DMODEL;
    float v[4];
    float s = 0.f, q = 0.f;
#pragma unroll
    for (int i = 0; i < 4; i++) {
        v[i] = xr[tid + i * 256];
        s += v[i];
        q += v[i] * v[i];
    }
    __shared__ float sh_s[256], sh_q[256];
    sh_s[tid] = s; sh_q[tid] = q;
    __syncthreads();
    for (int st = 128; st > 0; st >>= 1) {
        if (tid < st) { sh_s[tid] += sh_s[tid + st]; sh_q[tid] += sh_q[tid + st]; }
        __syncthreads();
    }
    float mean = sh_s[0] * (1.f / DMODEL);
    float var  = sh_q[0] * (1.f / DMODEL) - mean * mean;
    float rstd = rsqrtf(var + LN_EPS);
#pragma unroll
    for (int i = 0; i < 4; i++) {
        int c = tid + i * 256;
        xn[(size_t)row * DMODEL + c] = (v[i] - mean) * rstd * g[c] + b[c];
    }
}

// ---------- Tiled fp32 GEMM: C[M,N] = A[M,K]*B[K,N] (+resid if WM==1) ----------
template <int WM>
__global__ void gemm_tiled(const float* __restrict__ A, const float* __restrict__ B,
                           float* __restrict__ C, const float* __restrict__ resid,
                           int M, int N, int K) {
    __shared__ float As[16][64];
    __shared__ float Bs[16][64];
    int tid = threadIdx.x;
    int tx = tid & 15, ty = tid >> 4;
    int colBase = blockIdx.x * 64, rowBase = blockIdx.y * 64;
    float acc[4][4] = {};
    for (int k0 = 0; k0 < K; k0 += 16) {
#pragma unroll
        for (int l = tid; l < 64 * 16; l += 256) {   // A tile 64 rows x 16 k
            int r = l >> 4, kk = l & 15;
            As[kk][r] = A[(size_t)(rowBase + r) * K + k0 + kk];
        }
#pragma unroll
        for (int l = tid; l < 16 * 64; l += 256) {   // B tile 16 k x 64 cols
            int kk = l >> 6, c = l & 63;
            Bs[kk][c] = B[(size_t)(k0 + kk) * N + colBase + c];
        }
        __syncthreads();
#pragma unroll
        for (int kk = 0; kk < 16; kk++) {
            float4 a4 = *(const float4*)&As[kk][ty * 4];
            float4 b4 = *(const float4*)&Bs[kk][tx * 4];
            float av[4] = {a4.x, a4.y, a4.z, a4.w};
            float bv[4] = {b4.x, b4.y, b4.z, b4.w};
#pragma unroll
            for (int i = 0; i < 4; i++)
#pragma unroll
                for (int j = 0; j < 4; j++)
                    acc[i][j] += av[i] * bv[j];
        }
        __syncthreads();
    }
#pragma unroll
    for (int i = 0; i < 4; i++) {
        size_t row = rowBase + ty * 4 + i;
#pragma unroll
        for (int j = 0; j < 4; j++) {
            int col = colBase + tx * 4 + j;
            float v = acc[i][j];
            if (WM == 1) v += resid[row * N + col];
            C[row * N + col] = v;
        }
    }
}

// ---------- Causal depthwise conv(4) + SiLU ----------
__global__ void conv_silu(const float* __restrict__ xz, const float* __restrict__ cw,
                          const float* __restrict__ cb, float* __restrict__ xc) {
    int idx = blockIdx.x * 256 + threadIdx.x;
    int t = idx >> 11, d = idx & (DINNER - 1);
    float acc = cb[d];
#pragma unroll
    for (int k = 0; k < 4; k++) {
        int tt = t - 3 + k;
        if (tt >= 0) acc += xz[(size_t)tt * (2 * DINNER) + d] * cw[d * 4 + k];
    }
    xc[idx] = acc / (1.f + __expf(-acc));
}

// ---------- ssm[t, 0..32] = xc[t,:] @ W_x[2048,33], block per t ----------
__global__ void proj_ssm(const float* __restrict__ xc, const float* __restrict__ Wx,
                         float* __restrict__ ssm) {
    __shared__ float xcs[DINNER];
    __shared__ float part[33][8];
    int t = blockIdx.x, tid = threadIdx.x;
    for (int l = tid; l < DINNER; l += 256) xcs[l] = xc[(size_t)t * DINNER + l];
    __syncthreads();
    int c = tid >> 3, sl = tid & 7;
    float acc = 0.f;
    int k0 = sl * 256;
    for (int k = k0; k < k0 + 256; k++) acc += xcs[k] * Wx[(size_t)k * 33 + c];
    part[c][sl] = acc;
    if (tid < 8) {
        float a2 = 0.f;
        int kk0 = tid * 256;
        for (int k = kk0; k < kk0 + 256; k++) a2 += xcs[k] * Wx[(size_t)k * 33 + 32];
        part[32][tid] = a2;
    }
    __syncthreads();
    if (tid < 33) {
        float s = 0.f;
#pragma unroll
        for (int i = 0; i < 8; i++) s += part[tid][i];
        ssm[t * 33 + tid] = s;
    }
}

__device__ __forceinline__ float softplus_f(float pre) {
    return (pre > 20.f) ? pre : log1pf(__expf(pre));
}

// ---------- Scan pass 1: per (d, chunk) local scan -> P (prod a), S (local end) ----------
__global__ void scan_pass1(const float* __restrict__ ssm, const float* __restrict__ xc,
                           const float* __restrict__ Wdt, const float* __restrict__ bdt,
                           const float* __restrict__ Alog,
                           float* __restrict__ P, float* __restrict__ S) {
    int d = blockIdx.x * 256 + threadIdx.x;   // grid.x = 8
    int c = blockIdx.y;                        // 0..31
    float A[DSTATE], Pv[DSTATE], Sv[DSTATE];
#pragma unroll
    for (int n = 0; n < DSTATE; n++) {
        A[n] = -__expf(Alog[d * DSTATE + n]);
        Pv[n] = 1.f; Sv[n] = 0.f;
    }
    float wdt = Wdt[d], bd = bdt[d];
    int t0 = c * CLEN;
    for (int t = t0; t < t0 + CLEN; t++) {
        const float* srow = ssm + t * 33;
        float dt = softplus_f(srow[0] * wdt + bd);
        float dtxc = dt * xc[(size_t)t * DINNER + d];
#pragma unroll
        for (int n = 0; n < DSTATE; n++) {
            float a = __expf(dt * A[n]);
            Pv[n] *= a;
            Sv[n] = a * Sv[n] + dtxc * srow[1 + n];
        }
    }
    size_t base = ((size_t)c * DINNER + d) * DSTATE;
#pragma unroll
    for (int n = 0; n < DSTATE; n++) { P[base + n] = Pv[n]; S[base + n] = Sv[n]; }
}

// ---------- Scan pass 2: sequential over chunks per (d,n); P <- chunk-start state ----------
__global__ void scan_pass2(float* __restrict__ P, const float* __restrict__ S) {
    int idx = blockIdx.x * 256 + threadIdx.x;   // d*16+n, 32768 total
    float H = 0.f;
    for (int c = 0; c < NCHUNK; c++) {
        size_t o = (size_t)c * DINNER * DSTATE + idx;
        float Pc = P[o], Sc = S[o];
        P[o] = H;            // overwrite with start-of-chunk state
        H = Pc * H + Sc;
    }
}

// ---------- Scan pass 3: replay chunk from start state, fused epilogue ----------
__global__ void scan_pass3(const float* __restrict__ ssm, const float* __restrict__ xc,
                           const float* __restrict__ xz,
                           const float* __restrict__ Wdt, const float* __restrict__ bdt,
                           const float* __restrict__ Alog, const float* __restrict__ Dp,
                           const float* __restrict__ Hst, float* __restrict__ yf) {
    int d = blockIdx.x * 256 + threadIdx.x;
    int c = blockIdx.y;
    float A[DSTATE], h[DSTATE];
    size_t base = ((size_t)c * DINNER + d) * DSTATE;
#pragma unroll
    for (int n = 0; n < DSTATE; n++) {
        A[n] = -__expf(Alog[d * DSTATE + n]);
        h[n] = Hst[base + n];
    }
    float wdt = Wdt[d], bd = bdt[d], Dd = Dp[d];
    int t0 = c * CLEN;
    for (int t = t0; t < t0 + CLEN; t++) {
        const float* srow = ssm + t * 33;
        float dt = softplus_f(srow[0] * wdt + bd);
        float xcv = xc[(size_t)t * DINNER + d];
        float dtxc = dt * xcv;
        float y = 0.f;
#pragma unroll
        for (int n = 0; n < DSTATE; n++) {
            h[n] = __expf(dt * A[n]) * h[n] + dtxc * srow[1 + n];
            y += h[n] * srow[17 + n];
        }
        float z = xz[(size_t)t * (2 * DINNER) + DINNER + d];
        float sz = z / (1.f + __expf(-z));
        yf[(size_t)t * DINNER + d] = (y + xcv * Dd) * sz;
    }
}

extern "C" void kernel_launch(void* const* d_in, const int* in_sizes, int n_in,
                              void* d_out, int out_size, void* d_ws, size_t ws_size,
                              hipStream_t stream) {
    const float* x     = (const float*)d_in[0];
    const float* W_in  = (const float*)d_in[1];
    const float* convw = (const float*)d_in[2];
    const float* convb = (const float*)d_in[3];
    const float* W_x   = (const float*)d_in[4];
    const float* W_dt  = (const float*)d_in[5];
    const float* b_dt  = (const float*)d_in[6];
    const float* A_log = (const float*)d_in[7];
    const float* Dp    = (const float*)d_in[8];
    const float* W_out = (const float*)d_in[9];
    const float* ln_g  = (const float*)d_in[10];
    const float* ln_b  = (const float*)d_in[11];
    float* out = (float*)d_out;

    // fp32 workspace, 72.3 MB total (same footprint as the passing round-4 layout).
    // P/S chunk state reuses the xn buffer (dead after gemm_in).
    char* wsb = (char*)d_ws;
    float* xn  = (float*)(wsb);                    //  8 MB: 2048x1024 (dead after GEMM1)
    float* P   = (float*)(wsb);                    //  4 MB: 32x2048x16 (aliases xn)
    float* S   = (float*)(wsb + (4ull  << 20));    //  4 MB: 32x2048x16 (aliases xn)
    float* xz  = (float*)(wsb + (8ull  << 20));    // 32 MB: 2048x4096
    float* xc  = (float*)(wsb + (40ull << 20));    // 16 MB: 2048x2048
    float* yf  = (float*)(wsb + (56ull << 20));    // 16 MB: 2048x2048
    float* ssm = (float*)(wsb + (72ull << 20));    // 270 KB: 2048x33

    ln_kernel<<<T_LEN, 256, 0, stream>>>(x, ln_g, ln_b, xn);

    gemm_tiled<0><<<dim3((2 * DINNER) / 64, T_LEN / 64), 256, 0, stream>>>(
        xn, W_in, xz, nullptr, T_LEN, 2 * DINNER, DMODEL);

    conv_silu<<<(T_LEN * DINNER) / 256, 256, 0, stream>>>(xz, convw, convb, xc);

    proj_ssm<<<T_LEN, 256, 0, stream>>>(xc, W_x, ssm);

    scan_pass1<<<dim3(DINNER / 256, NCHUNK), 256, 0, stream>>>(
        ssm, xc, W_dt, b_dt, A_log, P, S);
    scan_pass2<<<(DINNER * DSTATE) / 256, 256, 0, stream>>>(P, S);
    scan_pass3<<<dim3(DINNER / 256, NCHUNK), 256, 0, stream>>>(
        ssm, xc, xz, W_dt, b_dt, A_log, Dp, P, yf);

    gemm_tiled<1><<<dim3(DMODEL / 64, T_LEN / 64), 256, 0, stream>>>(
        yf, W_out, out, x, T_LEN, DMODEL, DINNER);
}

// Round 6
// 434.278 us; speedup vs baseline: 11.5952x; 2.2356x over previous
//
#include <hip/hip_runtime.h>
#include <hip/hip_bf16.h>

typedef __hip_bfloat16 bf16;
typedef __attribute__((ext_vector_type(8))) short bf16x8;   // 8 bf16 (4 VGPRs)
typedef __attribute__((ext_vector_type(4))) float f32x4;

#define T_LEN 2048
#define DMODEL 1024
#define DINNER 2048
#define DSTATE 16
#define LN_EPS 1e-5f
#define NCHUNK 32
#define CLEN 64

#define GLOBAL_AS __attribute__((address_space(1)))
#define LDS_AS __attribute__((address_space(3)))

__device__ __forceinline__ void g2l16(void* lds, const void* g) {
    __builtin_amdgcn_global_load_lds((const GLOBAL_AS void*)g, (LDS_AS void*)lds, 16, 0, 0);
}

// ---------- transpose + fp32->bf16: W[K][N] -> Wt[N][K] ----------
__global__ void transpose_bf16(const float* __restrict__ W, bf16* __restrict__ Wt,
                               int K, int N) {
    __shared__ float t[32][33];
    int n0 = blockIdx.x * 32, k0 = blockIdx.y * 32;
    int tx = threadIdx.x & 31, ty4 = (threadIdx.x >> 5) * 4;
#pragma unroll
    for (int r = 0; r < 4; r++)
        t[ty4 + r][tx] = W[(size_t)(k0 + ty4 + r) * N + n0 + tx];
    __syncthreads();
#pragma unroll
    for (int r = 0; r < 4; r++)
        Wt[(size_t)(n0 + ty4 + r) * K + k0 + tx] = __float2bfloat16(t[tx][ty4 + r]);
}

// ---------- LayerNorm -> bf16 ----------
__global__ void ln_kernel(const float* __restrict__ x, const float* __restrict__ g,
                          const float* __restrict__ b, bf16* __restrict__ xn) {
    int row = blockIdx.x;
    int tid = threadIdx.x;
    const float* xr = x + (size_t)row * DMODEL;
    float v[4];
    float s = 0.f, q = 0.f;
#pragma unroll
    for (int i = 0; i < 4; i++) {
        v[i] = xr[tid + i * 256];
        s += v[i];
        q += v[i] * v[i];
    }
    __shared__ float sh_s[256], sh_q[256];
    sh_s[tid] = s; sh_q[tid] = q;
    __syncthreads();
    for (int st = 128; st > 0; st >>= 1) {
        if (tid < st) { sh_s[tid] += sh_s[tid + st]; sh_q[tid] += sh_q[tid + st]; }
        __syncthreads();
    }
    float mean = sh_s[0] * (1.f / DMODEL);
    float var  = sh_q[0] * (1.f / DMODEL) - mean * mean;
    float rstd = rsqrtf(var + LN_EPS);
#pragma unroll
    for (int i = 0; i < 4; i++) {
        int c = tid + i * 256;
        xn[(size_t)row * DMODEL + c] = __float2bfloat16((v[i] - mean) * rstd * g[c] + b[c]);
    }
}

// ---------- MFMA GEMM: C[M][N](f32) = A[M][K](bf16) * Bt[N][K](bf16)^T ----------
// m97 structure: 16B global_load_lds staging, XOR-swizzled LDS, 16x16x32 bf16 MFMA.
template <int BM, int BN, int WAVE_M, int WAVE_N, int WRITE_RESID>
__global__ void gemm_mfma(const bf16* __restrict__ A, const bf16* __restrict__ Bt,
                          float* __restrict__ C, const float* __restrict__ resid,
                          int M, int N, int K) {
    constexpr int WMsz = BM / WAVE_M;
    constexpr int WNsz = BN / WAVE_N;
    constexpr int TM = WMsz / 16;
    constexpr int TN = WNsz / 16;
    __shared__ short As[BM * 64];
    __shared__ short Bs[BN * 64];
    int tid = threadIdx.x;
    int lane = tid & 63, wave = tid >> 6;
    int wm = (wave / WAVE_N) * WMsz, wn = (wave % WAVE_N) * WNsz;
    int rowBase = blockIdx.y * BM, colBase = blockIdx.x * BN;

    f32x4 acc[TM][TN];
#pragma unroll
    for (int i = 0; i < TM; i++)
#pragma unroll
        for (int j = 0; j < TN; j++) acc[i][j] = f32x4{0.f, 0.f, 0.f, 0.f};

    int srow = tid >> 3;                 // row within a 32-row staging round
    int cc = (tid & 7) ^ (srow & 7);     // swizzled global k-chunk
    const int ldsoff = tid * 16;

    for (int k0 = 0; k0 < K; k0 += 64) {
#pragma unroll
        for (int j = 0; j < BM / 32; j++)
            g2l16((char*)As + j * 4096 + ldsoff,
                  A + (size_t)(rowBase + j * 32 + srow) * K + k0 + cc * 8);
#pragma unroll
        for (int j = 0; j < BN / 32; j++)
            g2l16((char*)Bs + j * 4096 + ldsoff,
                  Bt + (size_t)(colBase + j * 32 + srow) * K + k0 + cc * 8);
        __syncthreads();
#pragma unroll
        for (int ks = 0; ks < 2; ks++) {
            bf16x8 af[TM], bfr[TN];
#pragma unroll
            for (int i = 0; i < TM; i++) {
                int row = wm + i * 16 + (lane & 15);
                int slot = (ks * 4 + (lane >> 4)) ^ (row & 7);
                af[i] = *(const bf16x8*)((const char*)As + row * 128 + slot * 16);
            }
#pragma unroll
            for (int j = 0; j < TN; j++) {
                int row = wn + j * 16 + (lane & 15);
                int slot = (ks * 4 + (lane >> 4)) ^ (row & 7);
                bfr[j] = *(const bf16x8*)((const char*)Bs + row * 128 + slot * 16);
            }
#pragma unroll
            for (int i = 0; i < TM; i++)
#pragma unroll
                for (int j = 0; j < TN; j++)
                    acc[i][j] = __builtin_amdgcn_mfma_f32_16x16x32_bf16(
                        af[i], bfr[j], acc[i][j], 0, 0, 0);
        }
        __syncthreads();
    }
    int rq = lane >> 4, cn = lane & 15;
#pragma unroll
    for (int i = 0; i < TM; i++) {
#pragma unroll
        for (int j = 0; j < TN; j++) {
#pragma unroll
            for (int r = 0; r < 4; r++) {
                size_t row = rowBase + wm + i * 16 + rq * 4 + r;
                int col = colBase + wn + j * 16 + cn;
                float v = acc[i][j][r];
                if (WRITE_RESID) v += resid[row * N + col];
                C[row * N + col] = v;
            }
        }
    }
}

// ---------- Causal depthwise conv(4) + SiLU (fp32 xz -> fp32 xc) ----------
__global__ void conv_silu(const float* __restrict__ xz, const float* __restrict__ cw,
                          const float* __restrict__ cb, float* __restrict__ xc) {
    int idx = blockIdx.x * 256 + threadIdx.x;
    int t = idx >> 11, d = idx & (DINNER - 1);
    float acc = cb[d];
#pragma unroll
    for (int k = 0; k < 4; k++) {
        int tt = t - 3 + k;
        if (tt >= 0) acc += xz[(size_t)tt * (2 * DINNER) + d] * cw[d * 4 + k];
    }
    xc[idx] = acc / (1.f + __expf(-acc));
}

// ---------- ssm[t, 0..32] = xc[t,:] @ W_x[2048,33] ----------
__global__ void proj_ssm(const float* __restrict__ xc, const float* __restrict__ Wx,
                         float* __restrict__ ssm) {
    __shared__ float xcs[DINNER];
    __shared__ float part[33][8];
    int t = blockIdx.x, tid = threadIdx.x;
    for (int l = tid; l < DINNER; l += 256) xcs[l] = xc[(size_t)t * DINNER + l];
    __syncthreads();
    int c = tid >> 3, sl = tid & 7;
    float acc = 0.f;
    int k0 = sl * 256;
    for (int k = k0; k < k0 + 256; k++) acc += xcs[k] * Wx[(size_t)k * 33 + c];
    part[c][sl] = acc;
    if (tid < 8) {
        float a2 = 0.f;
        int kk0 = tid * 256;
        for (int k = kk0; k < kk0 + 256; k++) a2 += xcs[k] * Wx[(size_t)k * 33 + 32];
        part[32][tid] = a2;
    }
    __syncthreads();
    if (tid < 33) {
        float s = 0.f;
#pragma unroll
        for (int i = 0; i < 8; i++) s += part[tid][i];
        ssm[t * 33 + tid] = s;
    }
}

__device__ __forceinline__ float softplus_f(float pre) {
    return (pre > 20.f) ? pre : log1pf(__expf(pre));
}

// ---------- Scan pass 1: per-(d,chunk) local scan -> P (prod a), S (local end) ----------
__global__ void scan_pass1(const float* __restrict__ ssm, const float* __restrict__ xc,
                           const float* __restrict__ Wdt, const float* __restrict__ bdt,
                           const float* __restrict__ Alog,
                           float* __restrict__ P, float* __restrict__ S) {
    int d = blockIdx.x * 256 + threadIdx.x;
    int c = blockIdx.y;
    float A[DSTATE], Pv[DSTATE], Sv[DSTATE];
#pragma unroll
    for (int n = 0; n < DSTATE; n++) {
        A[n] = -__expf(Alog[d * DSTATE + n]);
        Pv[n] = 1.f; Sv[n] = 0.f;
    }
    float wdt = Wdt[d], bd = bdt[d];
    int t0 = c * CLEN;
    for (int t = t0; t < t0 + CLEN; t++) {
        const float* srow = ssm + t * 33;
        float dt = softplus_f(srow[0] * wdt + bd);
        float dtxc = dt * xc[(size_t)t * DINNER + d];
#pragma unroll
        for (int n = 0; n < DSTATE; n++) {
            float a = __expf(dt * A[n]);
            Pv[n] *= a;
            Sv[n] = a * Sv[n] + dtxc * srow[1 + n];
        }
    }
    size_t base = ((size_t)c * DINNER + d) * DSTATE;
#pragma unroll
    for (int n = 0; n < DSTATE; n++) { P[base + n] = Pv[n]; S[base + n] = Sv[n]; }
}

// ---------- Scan pass 2: sequential over 32 chunks per (d,n) ----------
__global__ void scan_pass2(float* __restrict__ P, const float* __restrict__ S) {
    int idx = blockIdx.x * 256 + threadIdx.x;
    float H = 0.f;
    for (int c = 0; c < NCHUNK; c++) {
        size_t o = (size_t)c * DINNER * DSTATE + idx;
        float Pc = P[o], Sc = S[o];
        P[o] = H;
        H = Pc * H + Sc;
    }
}

// ---------- Scan pass 3: replay chunk, fused epilogue, bf16 out ----------
__global__ void scan_pass3(const float* __restrict__ ssm, const float* __restrict__ xc,
                           const float* __restrict__ xz,
                           const float* __restrict__ Wdt, const float* __restrict__ bdt,
                           const float* __restrict__ Alog, const float* __restrict__ Dp,
                           const float* __restrict__ Hst, bf16* __restrict__ yf) {
    int d = blockIdx.x * 256 + threadIdx.x;
    int c = blockIdx.y;
    float A[DSTATE], h[DSTATE];
    size_t base = ((size_t)c * DINNER + d) * DSTATE;
#pragma unroll
    for (int n = 0; n < DSTATE; n++) {
        A[n] = -__expf(Alog[d * DSTATE + n]);
        h[n] = Hst[base + n];
    }
    float wdt = Wdt[d], bd = bdt[d], Dd = Dp[d];
    int t0 = c * CLEN;
    for (int t = t0; t < t0 + CLEN; t++) {
        const float* srow = ssm + t * 33;
        float dt = softplus_f(srow[0] * wdt + bd);
        float xcv = xc[(size_t)t * DINNER + d];
        float dtxc = dt * xcv;
        float y = 0.f;
#pragma unroll
        for (int n = 0; n < DSTATE; n++) {
            h[n] = __expf(dt * A[n]) * h[n] + dtxc * srow[1 + n];
            y += h[n] * srow[17 + n];
        }
        float z = xz[(size_t)t * (2 * DINNER) + DINNER + d];
        float sz = z / (1.f + __expf(-z));
        yf[(size_t)t * DINNER + d] = __float2bfloat16((y + xcv * Dd) * sz);
    }
}

extern "C" void kernel_launch(void* const* d_in, const int* in_sizes, int n_in,
                              void* d_out, int out_size, void* d_ws, size_t ws_size,
                              hipStream_t stream) {
    const float* x     = (const float*)d_in[0];
    const float* W_in  = (const float*)d_in[1];
    const float* convw = (const float*)d_in[2];
    const float* convb = (const float*)d_in[3];
    const float* W_x   = (const float*)d_in[4];
    const float* W_dt  = (const float*)d_in[5];
    const float* b_dt  = (const float*)d_in[6];
    const float* A_log = (const float*)d_in[7];
    const float* Dp    = (const float*)d_in[8];
    const float* W_out = (const float*)d_in[9];
    const float* ln_g  = (const float*)d_in[10];
    const float* ln_b  = (const float*)d_in[11];
    float* out = (float*)d_out;

    // 72.3 MB workspace (same proven footprint). P/S alias dead W_inT.
    char* wsb = (char*)d_ws;
    bf16*  xn    = (bf16*)(wsb);                    //  4 MB [dead after GEMM1]
    bf16*  WinT  = (bf16*)(wsb + (4ull  << 20));    //  8 MB [dead after GEMM1]
    float* P     = (float*)(wsb + (4ull  << 20));   //  4 MB (aliases WinT)
    float* S     = (float*)(wsb + (8ull  << 20));   //  4 MB (aliases WinT)
    bf16*  WoutT = (bf16*)(wsb + (12ull << 20));    //  4 MB
    float* xz    = (float*)(wsb + (16ull << 20));   // 32 MB
    float* xc    = (float*)(wsb + (48ull << 20));   // 16 MB
    bf16*  yf    = (bf16*)(wsb + (64ull << 20));    //  8 MB
    float* ssm   = (float*)(wsb + (72ull << 20));   // 270 KB

    transpose_bf16<<<dim3(4096 / 32, 1024 / 32), 256, 0, stream>>>(W_in, WinT, 1024, 4096);
    transpose_bf16<<<dim3(1024 / 32, 2048 / 32), 256, 0, stream>>>(W_out, WoutT, 2048, 1024);

    ln_kernel<<<T_LEN, 256, 0, stream>>>(x, ln_g, ln_b, xn);

    // GEMM1: xz[2048,4096] = xn[2048,1024] @ WinT[4096,1024]^T
    gemm_mfma<128, 128, 2, 2, 0><<<dim3(4096 / 128, 2048 / 128), 256, 0, stream>>>(
        xn, WinT, xz, nullptr, 2048, 4096, 1024);

    conv_silu<<<(T_LEN * DINNER) / 256, 256, 0, stream>>>(xz, convw, convb, xc);

    proj_ssm<<<T_LEN, 256, 0, stream>>>(xc, W_x, ssm);

    scan_pass1<<<dim3(DINNER / 256, NCHUNK), 256, 0, stream>>>(
        ssm, xc, W_dt, b_dt, A_log, P, S);
    scan_pass2<<<(DINNER * DSTATE) / 256, 256, 0, stream>>>(P, S);
    scan_pass3<<<dim3(DINNER / 256, NCHUNK), 256, 0, stream>>>(
        ssm, xc, xz, W_dt, b_dt, A_log, Dp, P, yf);

    // GEMM2: out[2048,1024] = yf[2048,2048] @ WoutT[1024,2048]^T + x
    gemm_mfma<64, 128, 1, 4, 1><<<dim3(1024 / 128, 2048 / 64), 256, 0, stream>>>(
        yf, WoutT, out, x, 2048, 1024, 2048);
}

// Round 7
// 325.196 us; speedup vs baseline: 15.4847x; 1.3354x over previous
//
#include <hip/hip_runtime.h>
#include <hip/hip_bf16.h>

typedef __hip_bfloat16 bf16;
typedef __attribute__((ext_vector_type(8))) short bf16x8;   // 8 bf16 (4 VGPRs)
typedef __attribute__((ext_vector_type(4))) float f32x4;

#define T_LEN 2048
#define DMODEL 1024
#define DINNER 2048
#define DSTATE 16
#define LN_EPS 1e-5f
#define NCHUNK 32
#define CLEN 64
#define SSTR 64   // ssm row stride (33 used, padded to 64)

#define GLOBAL_AS __attribute__((address_space(1)))
#define LDS_AS __attribute__((address_space(3)))

__device__ __forceinline__ void g2l16(void* lds, const void* g) {
    __builtin_amdgcn_global_load_lds((const GLOBAL_AS void*)g, (LDS_AS void*)lds, 16, 0, 0);
}

// ---------- transpose + fp32->bf16: W[K][N] -> Wt[N][K] ----------
__global__ void transpose_bf16(const float* __restrict__ W, bf16* __restrict__ Wt,
                               int K, int N) {
    __shared__ float t[32][33];
    int n0 = blockIdx.x * 32, k0 = blockIdx.y * 32;
    int tx = threadIdx.x & 31, ty4 = (threadIdx.x >> 5) * 4;
#pragma unroll
    for (int r = 0; r < 4; r++)
        t[ty4 + r][tx] = W[(size_t)(k0 + ty4 + r) * N + n0 + tx];
    __syncthreads();
#pragma unroll
    for (int r = 0; r < 4; r++)
        Wt[(size_t)(n0 + ty4 + r) * K + k0 + tx] = __float2bfloat16(t[tx][ty4 + r]);
}

// ---------- W_x[2048][33] -> WxT[64][2048] bf16, zero-pad rows 33..63 ----------
__global__ void transpose_wx(const float* __restrict__ W, bf16* __restrict__ Wt) {
    int idx = blockIdx.x * 256 + threadIdx.x;   // n*2048 + k, 131072 total
    int n = idx >> 11, k = idx & 2047;
    Wt[idx] = __float2bfloat16(n < 33 ? W[k * 33 + n] : 0.f);
}

// ---------- LayerNorm -> bf16 ----------
__global__ void ln_kernel(const float* __restrict__ x, const float* __restrict__ g,
                          const float* __restrict__ b, bf16* __restrict__ xn) {
    int row = blockIdx.x;
    int tid = threadIdx.x;
    const float* xr = x + (size_t)row * DMODEL;
    float v[4];
    float s = 0.f, q = 0.f;
#pragma unroll
    for (int i = 0; i < 4; i++) {
        v[i] = xr[tid + i * 256];
        s += v[i];
        q += v[i] * v[i];
    }
    __shared__ float sh_s[256], sh_q[256];
    sh_s[tid] = s; sh_q[tid] = q;
    __syncthreads();
    for (int st = 128; st > 0; st >>= 1) {
        if (tid < st) { sh_s[tid] += sh_s[tid + st]; sh_q[tid] += sh_q[tid + st]; }
        __syncthreads();
    }
    float mean = sh_s[0] * (1.f / DMODEL);
    float var  = sh_q[0] * (1.f / DMODEL) - mean * mean;
    float rstd = rsqrtf(var + LN_EPS);
#pragma unroll
    for (int i = 0; i < 4; i++) {
        int c = tid + i * 256;
        xn[(size_t)row * DMODEL + c] = __float2bfloat16((v[i] - mean) * rstd * g[c] + b[c]);
    }
}

// ---------- MFMA GEMM: C[M][N](f32) = A[M][K](bf16) * Bt[N][K](bf16)^T ----------
template <int BM, int BN, int WAVE_M, int WAVE_N, int WRITE_RESID>
__global__ void gemm_mfma(const bf16* __restrict__ A, const bf16* __restrict__ Bt,
                          float* __restrict__ C, const float* __restrict__ resid,
                          int M, int N, int K) {
    constexpr int WMsz = BM / WAVE_M;
    constexpr int WNsz = BN / WAVE_N;
    constexpr int TM = WMsz / 16;
    constexpr int TN = WNsz / 16;
    __shared__ short As[BM * 64];
    __shared__ short Bs[BN * 64];
    int tid = threadIdx.x;
    int lane = tid & 63, wave = tid >> 6;
    int wm = (wave / WAVE_N) * WMsz, wn = (wave % WAVE_N) * WNsz;
    int rowBase = blockIdx.y * BM, colBase = blockIdx.x * BN;

    f32x4 acc[TM][TN];
#pragma unroll
    for (int i = 0; i < TM; i++)
#pragma unroll
        for (int j = 0; j < TN; j++) acc[i][j] = f32x4{0.f, 0.f, 0.f, 0.f};

    int srow = tid >> 3;                 // row within a 32-row staging round
    int cc = (tid & 7) ^ (srow & 7);     // swizzled global k-chunk
    const int ldsoff = tid * 16;

    for (int k0 = 0; k0 < K; k0 += 64) {
#pragma unroll
        for (int j = 0; j < BM / 32; j++)
            g2l16((char*)As + j * 4096 + ldsoff,
                  A + (size_t)(rowBase + j * 32 + srow) * K + k0 + cc * 8);
#pragma unroll
        for (int j = 0; j < BN / 32; j++)
            g2l16((char*)Bs + j * 4096 + ldsoff,
                  Bt + (size_t)(colBase + j * 32 + srow) * K + k0 + cc * 8);
        __syncthreads();
#pragma unroll
        for (int ks = 0; ks < 2; ks++) {
            bf16x8 af[TM], bfr[TN];
#pragma unroll
            for (int i = 0; i < TM; i++) {
                int row = wm + i * 16 + (lane & 15);
                int slot = (ks * 4 + (lane >> 4)) ^ (row & 7);
                af[i] = *(const bf16x8*)((const char*)As + row * 128 + slot * 16);
            }
#pragma unroll
            for (int j = 0; j < TN; j++) {
                int row = wn + j * 16 + (lane & 15);
                int slot = (ks * 4 + (lane >> 4)) ^ (row & 7);
                bfr[j] = *(const bf16x8*)((const char*)Bs + row * 128 + slot * 16);
            }
#pragma unroll
            for (int i = 0; i < TM; i++)
#pragma unroll
                for (int j = 0; j < TN; j++)
                    acc[i][j] = __builtin_amdgcn_mfma_f32_16x16x32_bf16(
                        af[i], bfr[j], acc[i][j], 0, 0, 0);
        }
        __syncthreads();
    }
    int rq = lane >> 4, cn = lane & 15;
#pragma unroll
    for (int i = 0; i < TM; i++) {
#pragma unroll
        for (int j = 0; j < TN; j++) {
#pragma unroll
            for (int r = 0; r < 4; r++) {
                size_t row = rowBase + wm + i * 16 + rq * 4 + r;
                int col = colBase + wn + j * 16 + cn;
                float v = acc[i][j][r];
                if (WRITE_RESID) v += resid[row * N + col];
                C[row * N + col] = v;
            }
        }
    }
}

// ---------- Causal depthwise conv(4) + SiLU -> bf16 ----------
__global__ void conv_silu(const float* __restrict__ xz, const float* __restrict__ cw,
                          const float* __restrict__ cb, bf16* __restrict__ xc) {
    int idx = blockIdx.x * 256 + threadIdx.x;
    int t = idx >> 11, d = idx & (DINNER - 1);
    float acc = cb[d];
#pragma unroll
    for (int k = 0; k < 4; k++) {
        int tt = t - 3 + k;
        if (tt >= 0) acc += xz[(size_t)tt * (2 * DINNER) + d] * cw[d * 4 + k];
    }
    xc[idx] = __float2bfloat16(acc / (1.f + __expf(-acc)));
}

__device__ __forceinline__ float softplus_f(float pre) {
    return (pre > 20.f) ? pre : log1pf(__expf(pre));
}

// ---------- Scan pass 1: per-(d,chunk) local scan -> P (prod a), S (local end) ----------
__global__ void scan_pass1(const float* __restrict__ ssm, const bf16* __restrict__ xc,
                           const float* __restrict__ Wdt, const float* __restrict__ bdt,
                           const float* __restrict__ Alog,
                           float* __restrict__ P, float* __restrict__ S) {
    int d = blockIdx.x * 256 + threadIdx.x;
    int c = blockIdx.y;
    float A[DSTATE], Pv[DSTATE], Sv[DSTATE];
#pragma unroll
    for (int n = 0; n < DSTATE; n++) {
        A[n] = -__expf(Alog[d * DSTATE + n]);
        Pv[n] = 1.f; Sv[n] = 0.f;
    }
    float wdt = Wdt[d], bd = bdt[d];
    int t0 = c * CLEN;
    for (int t = t0; t < t0 + CLEN; t++) {
        const float* srow = ssm + (size_t)t * SSTR;
        float dt = softplus_f(srow[0] * wdt + bd);
        float dtxc = dt * (float)xc[(size_t)t * DINNER + d];
#pragma unroll
        for (int n = 0; n < DSTATE; n++) {
            float a = __expf(dt * A[n]);
            Pv[n] *= a;
            Sv[n] = a * Sv[n] + dtxc * srow[1 + n];
        }
    }
    size_t base = ((size_t)c * DINNER + d) * DSTATE;
#pragma unroll
    for (int n = 0; n < DSTATE; n++) { P[base + n] = Pv[n]; S[base + n] = Sv[n]; }
}

// ---------- Scan pass 2: sequential over 32 chunks per (d,n) ----------
__global__ void scan_pass2(float* __restrict__ P, const float* __restrict__ S) {
    int idx = blockIdx.x * 256 + threadIdx.x;
    float H = 0.f;
    for (int c = 0; c < NCHUNK; c++) {
        size_t o = (size_t)c * DINNER * DSTATE + idx;
        float Pc = P[o], Sc = S[o];
        P[o] = H;
        H = Pc * H + Sc;
    }
}

// ---------- Scan pass 3: replay chunk, fused epilogue, bf16 out ----------
__global__ void scan_pass3(const float* __restrict__ ssm, const bf16* __restrict__ xc,
                           const float* __restrict__ xz,
                           const float* __restrict__ Wdt, const float* __restrict__ bdt,
                           const float* __restrict__ Alog, const float* __restrict__ Dp,
                           const float* __restrict__ Hst, bf16* __restrict__ yf) {
    int d = blockIdx.x * 256 + threadIdx.x;
    int c = blockIdx.y;
    float A[DSTATE], h[DSTATE];
    size_t base = ((size_t)c * DINNER + d) * DSTATE;
#pragma unroll
    for (int n = 0; n < DSTATE; n++) {
        A[n] = -__expf(Alog[d * DSTATE + n]);
        h[n] = Hst[base + n];
    }
    float wdt = Wdt[d], bd = bdt[d], Dd = Dp[d];
    int t0 = c * CLEN;
    for (int t = t0; t < t0 + CLEN; t++) {
        const float* srow = ssm + (size_t)t * SSTR;
        float dt = softplus_f(srow[0] * wdt + bd);
        float xcv = (float)xc[(size_t)t * DINNER + d];
        float dtxc = dt * xcv;
        float y = 0.f;
#pragma unroll
        for (int n = 0; n < DSTATE; n++) {
            h[n] = __expf(dt * A[n]) * h[n] + dtxc * srow[1 + n];
            y += h[n] * srow[17 + n];
        }
        float z = xz[(size_t)t * (2 * DINNER) + DINNER + d];
        float sz = z / (1.f + __expf(-z));
        yf[(size_t)t * DINNER + d] = __float2bfloat16((y + xcv * Dd) * sz);
    }
}

extern "C" void kernel_launch(void* const* d_in, const int* in_sizes, int n_in,
                              void* d_out, int out_size, void* d_ws, size_t ws_size,
                              hipStream_t stream) {
    const float* x     = (const float*)d_in[0];
    const float* W_in  = (const float*)d_in[1];
    const float* convw = (const float*)d_in[2];
    const float* convb = (const float*)d_in[3];
    const float* W_x   = (const float*)d_in[4];
    const float* W_dt  = (const float*)d_in[5];
    const float* b_dt  = (const float*)d_in[6];
    const float* A_log = (const float*)d_in[7];
    const float* Dp    = (const float*)d_in[8];
    const float* W_out = (const float*)d_in[9];
    const float* ln_g  = (const float*)d_in[10];
    const float* ln_b  = (const float*)d_in[11];
    float* out = (float*)d_out;

    // 64.75 MB workspace (proven footprint 72.27 MB). P/S alias dead WinT.
    char* wsb = (char*)d_ws;
    bf16*  xn    = (bf16*)(wsb);                    //  4 MB [dead after GEMM1]
    bf16*  WinT  = (bf16*)(wsb + (4ull  << 20));    //  8 MB [dead after GEMM1]
    float* P     = (float*)(wsb + (4ull  << 20));   //  4 MB (aliases WinT)
    float* S     = (float*)(wsb + (8ull  << 20));   //  4 MB (aliases WinT)
    bf16*  WoutT = (bf16*)(wsb + (12ull << 20));    //  4 MB
    float* xz    = (float*)(wsb + (16ull << 20));   // 32 MB
    bf16*  xc    = (bf16*)(wsb + (48ull << 20));    //  8 MB
    bf16*  yf    = (bf16*)(wsb + (56ull << 20));    //  8 MB
    bf16*  WxT   = (bf16*)(wsb + (64ull << 20));    // 256 KB: 64x2048
    float* ssm   = (float*)(wsb + (64ull << 20) + (256ull << 10));  // 512 KB: 2048x64

    transpose_bf16<<<dim3(4096 / 32, 1024 / 32), 256, 0, stream>>>(W_in, WinT, 1024, 4096);
    transpose_bf16<<<dim3(1024 / 32, 2048 / 32), 256, 0, stream>>>(W_out, WoutT, 2048, 1024);
    transpose_wx<<<(64 * 2048) / 256, 256, 0, stream>>>(W_x, WxT);

    ln_kernel<<<T_LEN, 256, 0, stream>>>(x, ln_g, ln_b, xn);

    // GEMM1: xz[2048,4096] = xn[2048,1024] @ WinT[4096,1024]^T
    gemm_mfma<128, 128, 2, 2, 0><<<dim3(4096 / 128, 2048 / 128), 256, 0, stream>>>(
        xn, WinT, xz, nullptr, 2048, 4096, 1024);

    conv_silu<<<(T_LEN * DINNER) / 256, 256, 0, stream>>>(xz, convw, convb, xc);

    // ssm[2048,64] = xc[2048,2048] @ WxT[64,2048]^T  (cols 33..63 zero)
    gemm_mfma<32, 64, 2, 2, 0><<<dim3(1, 2048 / 32), 256, 0, stream>>>(
        xc, WxT, ssm, nullptr, 2048, 64, 2048);

    scan_pass1<<<dim3(DINNER / 256, NCHUNK), 256, 0, stream>>>(
        ssm, xc, W_dt, b_dt, A_log, P, S);
    scan_pass2<<<(DINNER * DSTATE) / 256, 256, 0, stream>>>(P, S);
    scan_pass3<<<dim3(DINNER / 256, NCHUNK), 256, 0, stream>>>(
        ssm, xc, xz, W_dt, b_dt, A_log, Dp, P, yf);

    // GEMM2: out[2048,1024] = yf[2048,2048] @ WoutT[1024,2048]^T + x
    gemm_mfma<64, 128, 1, 4, 1><<<dim3(1024 / 128, 2048 / 64), 256, 0, stream>>>(
        yf, WoutT, out, x, 2048, 1024, 2048);
}

// Round 8
// 279.397 us; speedup vs baseline: 18.0230x; 1.1639x over previous
//
#include <hip/hip_runtime.h>
#include <hip/hip_bf16.h>

typedef __hip_bfloat16 bf16;
typedef __attribute__((ext_vector_type(8))) short bf16x8;   // 8 bf16 (4 VGPRs)
typedef __attribute__((ext_vector_type(4))) float f32x4;

#define T_LEN 2048
#define DMODEL 1024
#define DINNER 2048
#define DSTATE 16
#define LN_EPS 1e-5f
#define NCHUNK 128
#define CLEN 16     // NCHUNK * CLEN == T_LEN
#define SSTR 64     // ssm row stride (33 used, padded to 64)

#define GLOBAL_AS __attribute__((address_space(1)))
#define LDS_AS __attribute__((address_space(3)))

__device__ __forceinline__ void g2l16(void* lds, const void* g) {
    __builtin_amdgcn_global_load_lds((const GLOBAL_AS void*)g, (LDS_AS void*)lds, 16, 0, 0);
}

// ---------- transpose + fp32->bf16: W[K][N] -> Wt[N][K] ----------
__global__ void transpose_bf16(const float* __restrict__ W, bf16* __restrict__ Wt,
                               int K, int N) {
    __shared__ float t[32][33];
    int n0 = blockIdx.x * 32, k0 = blockIdx.y * 32;
    int tx = threadIdx.x & 31, ty4 = (threadIdx.x >> 5) * 4;
#pragma unroll
    for (int r = 0; r < 4; r++)
        t[ty4 + r][tx] = W[(size_t)(k0 + ty4 + r) * N + n0 + tx];
    __syncthreads();
#pragma unroll
    for (int r = 0; r < 4; r++)
        Wt[(size_t)(n0 + ty4 + r) * K + k0 + tx] = __float2bfloat16(t[tx][ty4 + r]);
}

// ---------- W_x[2048][33] -> WxT[64][2048] bf16, zero-pad rows 33..63 ----------
__global__ void transpose_wx(const float* __restrict__ W, bf16* __restrict__ Wt) {
    int idx = blockIdx.x * 256 + threadIdx.x;
    int n = idx >> 11, k = idx & 2047;
    Wt[idx] = __float2bfloat16(n < 33 ? W[k * 33 + n] : 0.f);
}

// ---------- LayerNorm -> bf16 ----------
__global__ void ln_kernel(const float* __restrict__ x, const float* __restrict__ g,
                          const float* __restrict__ b, bf16* __restrict__ xn) {
    int row = blockIdx.x;
    int tid = threadIdx.x;
    const float* xr = x + (size_t)row * DMODEL;
    float v[4];
    float s = 0.f, q = 0.f;
#pragma unroll
    for (int i = 0; i < 4; i++) {
        v[i] = xr[tid + i * 256];
        s += v[i];
        q += v[i] * v[i];
    }
    __shared__ float sh_s[256], sh_q[256];
    sh_s[tid] = s; sh_q[tid] = q;
    __syncthreads();
    for (int st = 128; st > 0; st >>= 1) {
        if (tid < st) { sh_s[tid] += sh_s[tid + st]; sh_q[tid] += sh_q[tid + st]; }
        __syncthreads();
    }
    float mean = sh_s[0] * (1.f / DMODEL);
    float var  = sh_q[0] * (1.f / DMODEL) - mean * mean;
    float rstd = rsqrtf(var + LN_EPS);
#pragma unroll
    for (int i = 0; i < 4; i++) {
        int c = tid + i * 256;
        xn[(size_t)row * DMODEL + c] = __float2bfloat16((v[i] - mean) * rstd * g[c] + b[c]);
    }
}

// ---------- MFMA GEMM: C[M][N] = A[M][K](bf16) * Bt[N][K](bf16)^T ----------
// OUT_BF16: write bf16, else fp32. WRITE_RESID: add fp32 residual.
template <int BM, int BN, int WAVE_M, int WAVE_N, int WRITE_RESID, int OUT_BF16>
__global__ void gemm_mfma(const bf16* __restrict__ A, const bf16* __restrict__ Bt,
                          void* __restrict__ Cv, const float* __restrict__ resid,
                          int M, int N, int K) {
    constexpr int WMsz = BM / WAVE_M;
    constexpr int WNsz = BN / WAVE_N;
    constexpr int TM = WMsz / 16;
    constexpr int TN = WNsz / 16;
    __shared__ short As[BM * 64];
    __shared__ short Bs[BN * 64];
    int tid = threadIdx.x;
    int lane = tid & 63, wave = tid >> 6;
    int wm = (wave / WAVE_N) * WMsz, wn = (wave % WAVE_N) * WNsz;
    int rowBase = blockIdx.y * BM, colBase = blockIdx.x * BN;

    f32x4 acc[TM][TN];
#pragma unroll
    for (int i = 0; i < TM; i++)
#pragma unroll
        for (int j = 0; j < TN; j++) acc[i][j] = f32x4{0.f, 0.f, 0.f, 0.f};

    int srow = tid >> 3;
    int cc = (tid & 7) ^ (srow & 7);
    const int ldsoff = tid * 16;

    for (int k0 = 0; k0 < K; k0 += 64) {
#pragma unroll
        for (int j = 0; j < BM / 32; j++)
            g2l16((char*)As + j * 4096 + ldsoff,
                  A + (size_t)(rowBase + j * 32 + srow) * K + k0 + cc * 8);
#pragma unroll
        for (int j = 0; j < BN / 32; j++)
            g2l16((char*)Bs + j * 4096 + ldsoff,
                  Bt + (size_t)(colBase + j * 32 + srow) * K + k0 + cc * 8);
        __syncthreads();
#pragma unroll
        for (int ks = 0; ks < 2; ks++) {
            bf16x8 af[TM], bfr[TN];
#pragma unroll
            for (int i = 0; i < TM; i++) {
                int row = wm + i * 16 + (lane & 15);
                int slot = (ks * 4 + (lane >> 4)) ^ (row & 7);
                af[i] = *(const bf16x8*)((const char*)As + row * 128 + slot * 16);
            }
#pragma unroll
            for (int j = 0; j < TN; j++) {
                int row = wn + j * 16 + (lane & 15);
                int slot = (ks * 4 + (lane >> 4)) ^ (row & 7);
                bfr[j] = *(const bf16x8*)((const char*)Bs + row * 128 + slot * 16);
            }
#pragma unroll
            for (int i = 0; i < TM; i++)
#pragma unroll
                for (int j = 0; j < TN; j++)
                    acc[i][j] = __builtin_amdgcn_mfma_f32_16x16x32_bf16(
                        af[i], bfr[j], acc[i][j], 0, 0, 0);
        }
        __syncthreads();
    }
    int rq = lane >> 4, cn = lane & 15;
#pragma unroll
    for (int i = 0; i < TM; i++) {
#pragma unroll
        for (int j = 0; j < TN; j++) {
#pragma unroll
            for (int r = 0; r < 4; r++) {
                size_t row = rowBase + wm + i * 16 + rq * 4 + r;
                int col = colBase + wn + j * 16 + cn;
                float v = acc[i][j][r];
                if (WRITE_RESID) v += resid[row * N + col];
                if (OUT_BF16)
                    ((bf16*)Cv)[row * N + col] = __float2bfloat16(v);
                else
                    ((float*)Cv)[row * N + col] = v;
            }
        }
    }
}

// ---------- Causal depthwise conv(4) + SiLU (bf16 xz -> bf16 xc) ----------
__global__ void conv_silu(const bf16* __restrict__ xz, const float* __restrict__ cw,
                          const float* __restrict__ cb, bf16* __restrict__ xc) {
    int idx = blockIdx.x * 256 + threadIdx.x;
    int t = idx >> 11, d = idx & (DINNER - 1);
    float acc = cb[d];
#pragma unroll
    for (int k = 0; k < 4; k++) {
        int tt = t - 3 + k;
        if (tt >= 0) acc += (float)xz[(size_t)tt * (2 * DINNER) + d] * cw[d * 4 + k];
    }
    xc[idx] = __float2bfloat16(acc / (1.f + __expf(-acc)));
}

__device__ __forceinline__ float softplus_f(float pre) {
    return (pre > 20.f) ? pre : log1pf(__expf(pre));
}

// ---------- Scan pass 1: per-(d,chunk) local scan -> P[c][n][d], S[c][n][d] ----------
__global__ void scan_pass1(const float* __restrict__ ssm, const bf16* __restrict__ xc,
                           const float* __restrict__ Wdt, const float* __restrict__ bdt,
                           const float* __restrict__ Alog,
                           float* __restrict__ P, float* __restrict__ S) {
    int d = blockIdx.x * 256 + threadIdx.x;
    int c = blockIdx.y;
    float A[DSTATE], Pv[DSTATE], Sv[DSTATE];
#pragma unroll
    for (int n = 0; n < DSTATE; n++) {
        A[n] = -__expf(Alog[d * DSTATE + n]);
        Pv[n] = 1.f; Sv[n] = 0.f;
    }
    float wdt = Wdt[d], bd = bdt[d];
    int t0 = c * CLEN;
    for (int t = t0; t < t0 + CLEN; t++) {
        const float* srow = ssm + (size_t)t * SSTR;
        float dt = softplus_f(srow[0] * wdt + bd);
        float dtxc = dt * (float)xc[(size_t)t * DINNER + d];
#pragma unroll
        for (int n = 0; n < DSTATE; n++) {
            float a = __expf(dt * A[n]);
            Pv[n] *= a;
            Sv[n] = a * Sv[n] + dtxc * srow[1 + n];
        }
    }
    size_t base = (size_t)c * DINNER * DSTATE + d;   // [c][n][d] layout
#pragma unroll
    for (int n = 0; n < DSTATE; n++) {
        P[base + n * DINNER] = Pv[n];
        S[base + n * DINNER] = Sv[n];
    }
}

// ---------- Scan pass 2: sequential over chunks per (n,d) ----------
__global__ void scan_pass2(float* __restrict__ P, const float* __restrict__ S) {
    int idx = blockIdx.x * 256 + threadIdx.x;   // n*2048+d, 32768 total
    float H = 0.f;
    for (int c = 0; c < NCHUNK; c++) {
        size_t o = (size_t)c * DINNER * DSTATE + idx;
        float Pc = P[o], Sc = S[o];
        P[o] = H;
        H = Pc * H + Sc;
    }
}

// ---------- Scan pass 3: replay chunk from start state, fused epilogue ----------
__global__ void scan_pass3(const float* __restrict__ ssm, const bf16* __restrict__ xc,
                           const bf16* __restrict__ xz,
                           const float* __restrict__ Wdt, const float* __restrict__ bdt,
                           const float* __restrict__ Alog, const float* __restrict__ Dp,
                           const float* __restrict__ Hst, bf16* __restrict__ yf) {
    int d = blockIdx.x * 256 + threadIdx.x;
    int c = blockIdx.y;
    float A[DSTATE], h[DSTATE];
    size_t base = (size_t)c * DINNER * DSTATE + d;   // [c][n][d]
#pragma unroll
    for (int n = 0; n < DSTATE; n++) {
        A[n] = -__expf(Alog[d * DSTATE + n]);
        h[n] = Hst[base + n * DINNER];
    }
    float wdt = Wdt[d], bd = bdt[d], Dd = Dp[d];
    int t0 = c * CLEN;
    for (int t = t0; t < t0 + CLEN; t++) {
        const float* srow = ssm + (size_t)t * SSTR;
        float dt = softplus_f(srow[0] * wdt + bd);
        float xcv = (float)xc[(size_t)t * DINNER + d];
        float dtxc = dt * xcv;
        float y = 0.f;
#pragma unroll
        for (int n = 0; n < DSTATE; n++) {
            h[n] = __expf(dt * A[n]) * h[n] + dtxc * srow[1 + n];
            y += h[n] * srow[17 + n];
        }
        float z = (float)xz[(size_t)t * (2 * DINNER) + DINNER + d];
        float sz = z / (1.f + __expf(-z));
        yf[(size_t)t * DINNER + d] = __float2bfloat16((y + xcv * Dd) * sz);
    }
}

extern "C" void kernel_launch(void* const* d_in, const int* in_sizes, int n_in,
                              void* d_out, int out_size, void* d_ws, size_t ws_size,
                              hipStream_t stream) {
    const float* x     = (const float*)d_in[0];
    const float* W_in  = (const float*)d_in[1];
    const float* convw = (const float*)d_in[2];
    const float* convb = (const float*)d_in[3];
    const float* W_x   = (const float*)d_in[4];
    const float* W_dt  = (const float*)d_in[5];
    const float* b_dt  = (const float*)d_in[6];
    const float* A_log = (const float*)d_in[7];
    const float* Dp    = (const float*)d_in[8];
    const float* W_out = (const float*)d_in[9];
    const float* ln_g  = (const float*)d_in[10];
    const float* ln_b  = (const float*)d_in[11];
    float* out = (float*)d_out;

    // Workspace layout, max 72.25 MB (proven footprint 72.27 MB).
    // Aliasing: ssm over xn (dead after GEMM1), xc over WinT (dead after GEMM1).
    char* wsb = (char*)d_ws;
    bf16*  xn    = (bf16*)(wsb);                    // [0,4) MB; dead after GEMM1
    float* ssm   = (float*)(wsb);                   // [0,0.5) MB; written after GEMM1
    bf16*  WinT  = (bf16*)(wsb + (4ull  << 20));    // [4,12); dead after GEMM1
    bf16*  xc    = (bf16*)(wsb + (4ull  << 20));    // [4,12); written after GEMM1
    bf16*  WoutT = (bf16*)(wsb + (12ull << 20));    // [12,16)
    bf16*  xz    = (bf16*)(wsb + (16ull << 20));    // [16,32): 2048x4096 bf16
    float* P     = (float*)(wsb + (32ull << 20));   // [32,48): 128x16x2048
    float* S     = (float*)(wsb + (48ull << 20));   // [48,64)
    bf16*  yf    = (bf16*)(wsb + (64ull << 20));    // [64,72)
    bf16*  WxT   = (bf16*)(wsb + (72ull << 20));    // [72,72.25): 64x2048

    transpose_bf16<<<dim3(4096 / 32, 1024 / 32), 256, 0, stream>>>(W_in, WinT, 1024, 4096);
    transpose_bf16<<<dim3(1024 / 32, 2048 / 32), 256, 0, stream>>>(W_out, WoutT, 2048, 1024);
    transpose_wx<<<(64 * 2048) / 256, 256, 0, stream>>>(W_x, WxT);

    ln_kernel<<<T_LEN, 256, 0, stream>>>(x, ln_g, ln_b, xn);

    // GEMM1: xz[2048,4096](bf16) = xn[2048,1024] @ WinT[4096,1024]^T
    gemm_mfma<128, 128, 2, 2, 0, 1><<<dim3(4096 / 128, 2048 / 128), 256, 0, stream>>>(
        xn, WinT, xz, nullptr, 2048, 4096, 1024);

    conv_silu<<<(T_LEN * DINNER) / 256, 256, 0, stream>>>(xz, convw, convb, xc);

    // ssm[2048,64](f32) = xc[2048,2048] @ WxT[64,2048]^T (cols 33..63 zero)
    gemm_mfma<32, 64, 2, 2, 0, 0><<<dim3(1, 2048 / 32), 256, 0, stream>>>(
        xc, WxT, ssm, nullptr, 2048, 64, 2048);

    scan_pass1<<<dim3(DINNER / 256, NCHUNK), 256, 0, stream>>>(
        ssm, xc, W_dt, b_dt, A_log, P, S);
    scan_pass2<<<(DINNER * DSTATE) / 256, 256, 0, stream>>>(P, S);
    scan_pass3<<<dim3(DINNER / 256, NCHUNK), 256, 0, stream>>>(
        ssm, xc, xz, W_dt, b_dt, A_log, Dp, P, yf);

    // GEMM2: out[2048,1024](f32) = yf[2048,2048] @ WoutT[1024,2048]^T + x
    gemm_mfma<64, 128, 1, 4, 1, 0><<<dim3(1024 / 128, 2048 / 64), 256, 0, stream>>>(
        yf, WoutT, out, x, 2048, 1024, 2048);
}